// Round 8
// baseline (162.309 us; speedup 1.0000x reference)
//
#include <hip/hip_runtime.h>
#include <hip/hip_bf16.h>

// EfficientMultiScaleROIExtractor for MI355X (gfx950)
// fm: [1,64,120,120] f32, boxes: [4096,4] f32, MLP weights f32.
//
// K1 k_transpose_mean: CHW->HWC + per-block channel partial sums
// K2 k_ghead: global mean -> shared head -> folded f1 bias (f1pre[128])
// K3 k_fused: 256 threads = 4 waves per block, 2 boxes per block
//   (grid 2048 = 8 blocks/CU, 8192 waves total -> full residency).
//   Pool: 2 waves per box, 8 point-groups of 16 lanes; each group
//     recomputes its grid point inline (lockstep VALU) and the wave
//     fetches 4 points x 1 corner per VMEM instr (16 lanes x float4 =
//     1KB coalesced). Wave shfl reduce + cross-wave LDS sum.
//   MLP: block-wide phase parallelism over 2 boxes; activations
//     broadcast from LDS (wave-uniform), weights 256B-coalesced.
//   __launch_bounds__(256,6): VGPR cap ~85 — roomy, NO spills
//   (r6/r7 lesson: min-waves=8 clamped VGPR to 32 -> scratch traffic).

#define HW 120
#define NPIX (HW * HW)   // 14400

__global__ __launch_bounds__(256) void k_transpose_mean(
    const float* __restrict__ fm, float* __restrict__ fm_t,
    float* __restrict__ partial)
{
    __shared__ float tile[64][65];
    __shared__ float pr[4][64];
    const int t  = threadIdx.x;
    const int tx = t & 63;
    const int ty = t >> 6;
    const int pix0 = blockIdx.x * 64;   // 225 blocks * 64 pixels = 14400

    #pragma unroll
    for (int k = 0; k < 16; ++k) {
        const int c = k * 4 + ty;
        tile[c][tx] = fm[c * NPIX + pix0 + tx];   // coalesced read
    }
    __syncthreads();
    #pragma unroll
    for (int k = 0; k < 16; ++k) {
        const int p = k * 4 + ty;
        fm_t[(pix0 + p) * 64 + tx] = tile[tx][p]; // coalesced write
    }
    float s = 0.f;
    #pragma unroll
    for (int k = 0; k < 16; ++k) s += tile[tx][ty * 16 + k];
    pr[ty][tx] = s;
    __syncthreads();
    if (t < 64)
        partial[blockIdx.x * 64 + t] = pr[0][t] + pr[1][t] + pr[2][t] + pr[3][t];
}

__global__ __launch_bounds__(256) void k_ghead(
    const float* __restrict__ partial,
    const float* __restrict__ w1, const float* __restrict__ b1,
    const float* __restrict__ w2, const float* __restrict__ b2,
    const float* __restrict__ p1, const float* __restrict__ pb1,
    float* __restrict__ f1pre)
{
    __shared__ float pr[4][64];
    __shared__ float g[64];
    __shared__ float h[128];
    __shared__ float gh[64];
    const int t = threadIdx.x;
    const int c = t & 63, q = t >> 6;
    float s = 0.f;
    for (int b = q; b < 225; b += 4) s += partial[b * 64 + c];
    pr[q][c] = s;
    __syncthreads();
    if (t < 64) g[t] = (pr[0][t] + pr[1][t] + pr[2][t] + pr[3][t]) * (1.f / 14400.f);
    __syncthreads();
    if (t < 128) {
        float a = b1[t];
        #pragma unroll 8
        for (int cc = 0; cc < 64; ++cc) a = fmaf(g[cc], w1[cc * 128 + t], a);
        h[t] = fmaxf(a, 0.f);
    }
    __syncthreads();
    if (t < 64) {
        float a = b2[t];
        #pragma unroll 8
        for (int k = 0; k < 128; ++k) a = fmaf(h[k], w2[k * 64 + t], a);
        gh[t] = fmaxf(a, 0.f);
    }
    __syncthreads();
    if (t < 128) {
        float a = pb1[t];
        #pragma unroll 8
        for (int j = 0; j < 64; ++j) a = fmaf(gh[j], p1[(192 + j) * 128 + t], a);
        f1pre[t] = a;   // no relu: relu happens after cat@p1 contribution
    }
}

// One scale's gather with 8 point-groups (2 waves per box). Each 16-lane
// group walks lp = g8, g8+8, ... recomputing the point's bilinear setup
// inline (lockstep within the group). Returns wave-partial sum (over the
// wave's 4 groups) valid in pg==0 lanes after the shfl reduce.
template <int R>
__device__ __forceinline__ float4 gather8(
    const char* __restrict__ fb, int g8,
    float cx, float cy, float bw2, float bh2)
{
    constexpr float invR = 1.f / (float)R;
    constexpr float s2   = invR * invR;          // folds the mean
    float ax = 0.f, ay = 0.f, az = 0.f, aw = 0.f;
    #pragma unroll 2
    for (int lp = g8; lp < R * R; lp += 8) {
        const int i = lp / R;                    // constexpr R -> magic mul
        const int j = lp - i * R;
        const float liny = (float)(2 * i + 1) * invR - 1.f;
        const float linx = (float)(2 * j + 1) * invR - 1.f;
        const float gy = cy + bh2 * liny;
        const float gx = cx + bw2 * linx;
        const float iy = ((gy + 1.f) * 120.f - 1.f) * 0.5f;
        const float ix = ((gx + 1.f) * 120.f - 1.f) * 0.5f;
        const float y0f = floorf(iy), x0f = floorf(ix);
        const float wy = iy - y0f,  wx = ix - x0f;
        const int y0 = (int)y0f, x0 = (int)x0f;
        const float vy0 = (y0 >= 0 && y0 < HW)      ? 1.f : 0.f;
        const float vy1 = (y0 >= -1 && y0 < HW - 1) ? 1.f : 0.f;
        const float vx0 = (x0 >= 0 && x0 < HW)      ? 1.f : 0.f;
        const float vx1 = (x0 >= -1 && x0 < HW - 1) ? 1.f : 0.f;
        const int x0c = min(max(x0, 0), HW - 1);
        const int x1c = min(max(x0 + 1, 0), HW - 1);
        const int y0c = min(max(y0, 0), HW - 1);
        const int y1c = min(max(y0 + 1, 0), HW - 1);
        const int o00 = (y0c * HW + x0c) * 256;  // one HWC pixel = 256B
        const int o01 = (y0c * HW + x1c) * 256;
        const int o10 = (y1c * HW + x0c) * 256;
        const int o11 = (y1c * HW + x1c) * 256;
        const float w00 = (1.f - wx) * (1.f - wy) * s2 * (vy0 * vx0);
        const float w01 = wx * (1.f - wy) * s2 * (vy0 * vx1);
        const float w10 = (1.f - wx) * wy * s2 * (vy1 * vx0);
        const float w11 = wx * wy * s2 * (vy1 * vx1);
        const float4 v0 = *(const float4*)(fb + o00);
        const float4 v1 = *(const float4*)(fb + o01);
        const float4 v2 = *(const float4*)(fb + o10);
        const float4 v3 = *(const float4*)(fb + o11);
        ax = fmaf(w00, v0.x, ax); ay = fmaf(w00, v0.y, ay);
        az = fmaf(w00, v0.z, az); aw = fmaf(w00, v0.w, aw);
        ax = fmaf(w01, v1.x, ax); ay = fmaf(w01, v1.y, ay);
        az = fmaf(w01, v1.z, az); aw = fmaf(w01, v1.w, aw);
        ax = fmaf(w10, v2.x, ax); ay = fmaf(w10, v2.y, ay);
        az = fmaf(w10, v2.z, az); aw = fmaf(w10, v2.w, aw);
        ax = fmaf(w11, v3.x, ax); ay = fmaf(w11, v3.y, ay);
        az = fmaf(w11, v3.z, az); aw = fmaf(w11, v3.w, aw);
    }
    // combine this wave's 4 point-groups (lanes l, l^16, l^32, l^48)
    ax += __shfl_xor(ax, 16, 64); ay += __shfl_xor(ay, 16, 64);
    az += __shfl_xor(az, 16, 64); aw += __shfl_xor(aw, 16, 64);
    ax += __shfl_xor(ax, 32, 64); ay += __shfl_xor(ay, 32, 64);
    az += __shfl_xor(az, 32, 64); aw += __shfl_xor(aw, 32, 64);
    return make_float4(ax, ay, az, aw);
}

__global__ __launch_bounds__(256, 6) void k_fused(
    const float* __restrict__ fm_t, const float* __restrict__ boxes,
    const float* __restrict__ w1, const float* __restrict__ b1,
    const float* __restrict__ w2, const float* __restrict__ b2,
    const float* __restrict__ p1, const float* __restrict__ f1pre,
    const float* __restrict__ p2, const float* __restrict__ pb2,
    float* __restrict__ out, int N)
{
    __shared__ __align__(16) float xpart[2][2][192]; // per-box per-half pooled partials
    __shared__ __align__(16) float xbuf[2][192];     // pooled [3][64] per box
    __shared__ __align__(16) float hbuf[2][384];     // H [3][128] per box
    __shared__ __align__(16) float cbuf[2][192];     // cat per box
    __shared__ __align__(16) float fbuf[2][128];     // F per box
    __shared__ __align__(16) float opart[2][2][64];  // L4 split-K partials

    const int t    = threadIdx.x;
    const int lane = t & 63;
    const int w    = t >> 6;        // wave 0..3
    const int n0   = blockIdx.x * 2;

    // ---------------- pool: 2 waves per box ----------------
    {
        const int b  = w >> 1;      // box slot 0..1
        const int hf = w & 1;       // which half of the points
        const int qc = lane & 15;   // channel quad
        const int pg = lane >> 4;   // point group within wave
        const int g8 = hf * 4 + pg; // global point group 0..7
        const int n  = n0 + b;

        if (n < N) {
            const float4 bx = reinterpret_cast<const float4*>(boxes)[n];
            const float x1 = bx.x / 960.f * 2.f - 1.f;
            const float y1 = bx.y / 960.f * 2.f - 1.f;
            const float x2 = bx.z / 960.f * 2.f - 1.f;
            const float y2 = bx.w / 960.f * 2.f - 1.f;
            const float cx  = (x1 + x2) * 0.5f;
            const float cy  = (y1 + y2) * 0.5f;
            const float bw2 = fmaxf(x2 - x1, 1e-6f) * 0.5f;
            const float bh2 = fmaxf(y2 - y1, 1e-6f) * 0.5f;
            const char* fb = (const char*)fm_t + qc * 16;

            const float4 r0 = gather8<3>(fb, g8, cx, cy, bw2, bh2);
            if (pg == 0) *(float4*)(&xpart[b][hf][4 * qc]) = r0;
            const float4 r1 = gather8<7>(fb, g8, cx, cy, bw2, bh2);
            if (pg == 0) *(float4*)(&xpart[b][hf][64 + 4 * qc]) = r1;
            const float4 r2 = gather8<11>(fb, g8, cx, cy, bw2, bh2);
            if (pg == 0) *(float4*)(&xpart[b][hf][128 + 4 * qc]) = r2;
        } else if (pg == 0) {
            const float4 z = make_float4(0.f, 0.f, 0.f, 0.f);
            *(float4*)(&xpart[b][hf][4 * qc]) = z;
            *(float4*)(&xpart[b][hf][64 + 4 * qc]) = z;
            *(float4*)(&xpart[b][hf][128 + 4 * qc]) = z;
        }
    }
    __syncthreads();

    // sum the two halves: 2 boxes x 192 = 384 values
    for (int i = t; i < 384; i += 256) {
        const int b = i / 192, r = i - b * 192;
        xbuf[b][r] = xpart[b][0][r] + xpart[b][1][r];
    }
    __syncthreads();

    // ---------------- L1: 2 boxes x 3 scales x 128 outs = 768 = 3 per thread ----
    {
        const int k  = t & 127;          // output column
        const int wp = t >> 7;           // 0..1
        // groups G = wp, wp+2, wp+4 -> (box = G/3, scale = G%3)
        const int G0 = wp,     b0 = G0 / 3, s0 = G0 - 3 * b0;
        const int G1 = wp + 2, b1_ = G1 / 3, s1_ = G1 - 3 * b1_;
        const int G2 = wp + 4, b2_ = G2 / 3, s2_ = G2 - 3 * b2_;
        const float* xb0 = xbuf[b0] + s0 * 64;
        const float* xb1 = xbuf[b1_] + s1_ * 64;
        const float* xb2 = xbuf[b2_] + s2_ * 64;
        const float bias = b1[k];
        float a0 = bias, a1 = bias, a2 = bias;
        #pragma unroll 4
        for (int c4 = 0; c4 < 16; ++c4) {
            const float4 xv0 = *(const float4*)(xb0 + 4 * c4);  // uniform -> bcast
            const float4 xv1 = *(const float4*)(xb1 + 4 * c4);
            const float4 xv2 = *(const float4*)(xb2 + 4 * c4);
            #define W1LD(CI) w1[(4 * c4 + CI) * 128 + k]
            { const float wv = W1LD(0);
              a0 = fmaf(xv0.x, wv, a0); a1 = fmaf(xv1.x, wv, a1); a2 = fmaf(xv2.x, wv, a2); }
            { const float wv = W1LD(1);
              a0 = fmaf(xv0.y, wv, a0); a1 = fmaf(xv1.y, wv, a1); a2 = fmaf(xv2.y, wv, a2); }
            { const float wv = W1LD(2);
              a0 = fmaf(xv0.z, wv, a0); a1 = fmaf(xv1.z, wv, a1); a2 = fmaf(xv2.z, wv, a2); }
            { const float wv = W1LD(3);
              a0 = fmaf(xv0.w, wv, a0); a1 = fmaf(xv1.w, wv, a1); a2 = fmaf(xv2.w, wv, a2); }
            #undef W1LD
        }
        hbuf[b0][s0 * 128 + k]   = fmaxf(a0, 0.f);
        hbuf[b1_][s1_ * 128 + k] = fmaxf(a1, 0.f);
        hbuf[b2_][s2_ * 128 + k] = fmaxf(a2, 0.f);
    }
    __syncthreads();

    // ---------------- L2: 2 boxes x 3 scales x 64 outs = 384 ----------------
    {
        const int co = lane;             // output column
        const float bias = b2[co];
        {   // rep0: G = t>>6 in 0..3
            const int G = t >> 6;
            const int b = G / 3, s = G - 3 * (G / 3);
            const float* hb = hbuf[b] + s * 128;
            float a = bias;
            #pragma unroll 4
            for (int c4 = 0; c4 < 32; ++c4) {
                const float4 hv = *(const float4*)(hb + 4 * c4);
                a = fmaf(hv.x, w2[(4 * c4 + 0) * 64 + co], a);
                a = fmaf(hv.y, w2[(4 * c4 + 1) * 64 + co], a);
                a = fmaf(hv.z, w2[(4 * c4 + 2) * 64 + co], a);
                a = fmaf(hv.w, w2[(4 * c4 + 3) * 64 + co], a);
            }
            cbuf[b][s * 64 + co] = fmaxf(a, 0.f);
        }
        if (t < 128) {  // rep1: G = 4 + (t>>6) in 4..5
            const int G = 4 + (t >> 6);
            const int b = G / 3, s = G - 3 * (G / 3);
            const float* hb = hbuf[b] + s * 128;
            float a = bias;
            #pragma unroll 4
            for (int c4 = 0; c4 < 32; ++c4) {
                const float4 hv = *(const float4*)(hb + 4 * c4);
                a = fmaf(hv.x, w2[(4 * c4 + 0) * 64 + co], a);
                a = fmaf(hv.y, w2[(4 * c4 + 1) * 64 + co], a);
                a = fmaf(hv.z, w2[(4 * c4 + 2) * 64 + co], a);
                a = fmaf(hv.w, w2[(4 * c4 + 3) * 64 + co], a);
            }
            cbuf[b][s * 64 + co] = fmaxf(a, 0.f);
        }
    }
    __syncthreads();

    // ---------------- L3: 2 boxes x 128 outs = 256 = 1 per thread ----------------
    {
        const int k = t & 127;
        const int b = t >> 7;
        const float* cb = cbuf[b];
        float a = f1pre[k];              // includes pb1 + global-branch term
        #pragma unroll 4
        for (int q4 = 0; q4 < 48; ++q4) {
            const float4 cv = *(const float4*)(cb + 4 * q4);
            a = fmaf(cv.x, p1[(4 * q4 + 0) * 128 + k], a);
            a = fmaf(cv.y, p1[(4 * q4 + 1) * 128 + k], a);
            a = fmaf(cv.z, p1[(4 * q4 + 2) * 128 + k], a);
            a = fmaf(cv.w, p1[(4 * q4 + 3) * 128 + k], a);
        }
        fbuf[b][k] = fmaxf(a, 0.f);
    }
    __syncthreads();

    // ---------------- L4: 2 boxes x 64 outs, K=128 split across 2 halves ----------
    {
        const int co = lane;
        const int bb = (t >> 6) & 1;     // box (uniform per wave)
        const int kh = t >> 7;           // K-half (uniform per wave)
        const float* fbp = fbuf[bb] + kh * 64;
        float a = kh ? 0.f : pb2[co];
        #pragma unroll 4
        for (int j4 = 0; j4 < 16; ++j4) {
            const float4 fv = *(const float4*)(fbp + 4 * j4);
            a = fmaf(fv.x, p2[(kh * 64 + 4 * j4 + 0) * 64 + co], a);
            a = fmaf(fv.y, p2[(kh * 64 + 4 * j4 + 1) * 64 + co], a);
            a = fmaf(fv.z, p2[(kh * 64 + 4 * j4 + 2) * 64 + co], a);
            a = fmaf(fv.w, p2[(kh * 64 + 4 * j4 + 3) * 64 + co], a);
        }
        opart[kh][bb][co] = a;
    }
    __syncthreads();
    if (t < 128) {
        const int co = lane;
        const int bb = t >> 6;
        const int n  = n0 + bb;
        if (n < N)
            out[n * 64 + co] = fmaxf(opart[0][bb][co] + opart[1][bb][co], 0.f);
    }
}

extern "C" void kernel_launch(void* const* d_in, const int* in_sizes, int n_in,
                              void* d_out, int out_size, void* d_ws, size_t ws_size,
                              hipStream_t stream)
{
    const float* fm    = (const float*)d_in[0];
    const float* boxes = (const float*)d_in[1];
    const float* w1    = (const float*)d_in[2];
    const float* b1    = (const float*)d_in[3];
    const float* w2    = (const float*)d_in[4];
    const float* b2    = (const float*)d_in[5];
    const float* p1    = (const float*)d_in[6];
    const float* pb1   = (const float*)d_in[7];
    const float* p2    = (const float*)d_in[8];
    const float* pb2   = (const float*)d_in[9];
    float* out = (float*)d_out;

    const int N = in_sizes[1] / 4;       // 4096

    float* ws      = (float*)d_ws;
    float* fm_t    = ws;                         // 921600 floats
    float* partial = fm_t + 921600;              // 14400
    float* f1pre   = partial + 14400;            // 128

    k_transpose_mean<<<NPIX / 64, 256, 0, stream>>>(fm, fm_t, partial);
    k_ghead<<<1, 256, 0, stream>>>(partial, w1, b1, w2, b2, p1, pb1, f1pre);
    k_fused<<<(N + 1) / 2, 256, 0, stream>>>(fm_t, boxes, w1, b1, w2, b2,
                                             p1, f1pre, p2, pb2, out, N);
}

// Round 9
// 160.443 us; speedup vs baseline: 1.0116x; 1.0116x over previous
//
#include <hip/hip_runtime.h>
#include <hip/hip_bf16.h>

// EfficientMultiScaleROIExtractor for MI355X (gfx950)
// fm: [1,64,120,120] f32, boxes: [4096,4] f32, MLP weights f32.
//
// K1 k_transpose_mean: CHW->HWC + per-block channel partial sums
// K2 k_ghead: global mean -> shared head -> folded f1 bias (f1pre[128])
// K3 k_fused: 256 threads = 4 waves per block, 2 boxes per block
//   (grid 2048 = 8 blocks/CU, 8192 waves total -> full residency).
//   Pool: 2 waves per box, 8 point-groups of 16 lanes; each group
//     recomputes its grid point inline (lockstep VALU) and the wave
//     fetches 4 points x 1 corner per VMEM instr (16 lanes x float4 =
//     1KB coalesced). Wave shfl reduce + cross-wave LDS sum.
//   MLP: block-wide phase parallelism over 2 boxes; activations
//     broadcast from LDS (wave-uniform), weights 256B-coalesced.
//   PLAIN __launch_bounds__(256): r6/r7/r8 proved ANY min-waves hint
//   makes the allocator spill (WRITE_SIZE 5-12MB of scratch); r5's
//   unhinted build allocated 60 VGPR with zero spill. Natural <=64
//   VGPR gives 8 waves/SIMD eligibility anyway.

#define HW 120
#define NPIX (HW * HW)   // 14400

__global__ __launch_bounds__(256) void k_transpose_mean(
    const float* __restrict__ fm, float* __restrict__ fm_t,
    float* __restrict__ partial)
{
    __shared__ float tile[64][65];
    __shared__ float pr[4][64];
    const int t  = threadIdx.x;
    const int tx = t & 63;
    const int ty = t >> 6;
    const int pix0 = blockIdx.x * 64;   // 225 blocks * 64 pixels = 14400

    #pragma unroll
    for (int k = 0; k < 16; ++k) {
        const int c = k * 4 + ty;
        tile[c][tx] = fm[c * NPIX + pix0 + tx];   // coalesced read
    }
    __syncthreads();
    #pragma unroll
    for (int k = 0; k < 16; ++k) {
        const int p = k * 4 + ty;
        fm_t[(pix0 + p) * 64 + tx] = tile[tx][p]; // coalesced write
    }
    float s = 0.f;
    #pragma unroll
    for (int k = 0; k < 16; ++k) s += tile[tx][ty * 16 + k];
    pr[ty][tx] = s;
    __syncthreads();
    if (t < 64)
        partial[blockIdx.x * 64 + t] = pr[0][t] + pr[1][t] + pr[2][t] + pr[3][t];
}

__global__ __launch_bounds__(256) void k_ghead(
    const float* __restrict__ partial,
    const float* __restrict__ w1, const float* __restrict__ b1,
    const float* __restrict__ w2, const float* __restrict__ b2,
    const float* __restrict__ p1, const float* __restrict__ pb1,
    float* __restrict__ f1pre)
{
    __shared__ float pr[4][64];
    __shared__ float g[64];
    __shared__ float h[128];
    __shared__ float gh[64];
    const int t = threadIdx.x;
    const int c = t & 63, q = t >> 6;
    float s = 0.f;
    for (int b = q; b < 225; b += 4) s += partial[b * 64 + c];
    pr[q][c] = s;
    __syncthreads();
    if (t < 64) g[t] = (pr[0][t] + pr[1][t] + pr[2][t] + pr[3][t]) * (1.f / 14400.f);
    __syncthreads();
    if (t < 128) {
        float a = b1[t];
        #pragma unroll 8
        for (int cc = 0; cc < 64; ++cc) a = fmaf(g[cc], w1[cc * 128 + t], a);
        h[t] = fmaxf(a, 0.f);
    }
    __syncthreads();
    if (t < 64) {
        float a = b2[t];
        #pragma unroll 8
        for (int k = 0; k < 128; ++k) a = fmaf(h[k], w2[k * 64 + t], a);
        gh[t] = fmaxf(a, 0.f);
    }
    __syncthreads();
    if (t < 128) {
        float a = pb1[t];
        #pragma unroll 8
        for (int j = 0; j < 64; ++j) a = fmaf(gh[j], p1[(192 + j) * 128 + t], a);
        f1pre[t] = a;   // no relu: relu happens after cat@p1 contribution
    }
}

// One scale's gather with 8 point-groups (2 waves per box). Each 16-lane
// group walks lp = g8, g8+8, ... recomputing the point's bilinear setup
// inline (lockstep within the group). Returns wave-partial sum (over the
// wave's 4 groups) valid in pg==0 lanes after the shfl reduce.
template <int R>
__device__ __forceinline__ float4 gather8(
    const char* __restrict__ fb, int g8,
    float cx, float cy, float bw2, float bh2)
{
    constexpr float invR = 1.f / (float)R;
    constexpr float s2   = invR * invR;          // folds the mean
    float ax = 0.f, ay = 0.f, az = 0.f, aw = 0.f;
    #pragma unroll 2
    for (int lp = g8; lp < R * R; lp += 8) {
        const int i = lp / R;                    // constexpr R -> magic mul
        const int j = lp - i * R;
        const float liny = (float)(2 * i + 1) * invR - 1.f;
        const float linx = (float)(2 * j + 1) * invR - 1.f;
        const float gy = cy + bh2 * liny;
        const float gx = cx + bw2 * linx;
        const float iy = ((gy + 1.f) * 120.f - 1.f) * 0.5f;
        const float ix = ((gx + 1.f) * 120.f - 1.f) * 0.5f;
        const float y0f = floorf(iy), x0f = floorf(ix);
        const float wy = iy - y0f,  wx = ix - x0f;
        const int y0 = (int)y0f, x0 = (int)x0f;
        const float vy0 = (y0 >= 0 && y0 < HW)      ? 1.f : 0.f;
        const float vy1 = (y0 >= -1 && y0 < HW - 1) ? 1.f : 0.f;
        const float vx0 = (x0 >= 0 && x0 < HW)      ? 1.f : 0.f;
        const float vx1 = (x0 >= -1 && x0 < HW - 1) ? 1.f : 0.f;
        const int x0c = min(max(x0, 0), HW - 1);
        const int x1c = min(max(x0 + 1, 0), HW - 1);
        const int y0c = min(max(y0, 0), HW - 1);
        const int y1c = min(max(y0 + 1, 0), HW - 1);
        const int o00 = (y0c * HW + x0c) * 256;  // one HWC pixel = 256B
        const int o01 = (y0c * HW + x1c) * 256;
        const int o10 = (y1c * HW + x0c) * 256;
        const int o11 = (y1c * HW + x1c) * 256;
        const float w00 = (1.f - wx) * (1.f - wy) * s2 * (vy0 * vx0);
        const float w01 = wx * (1.f - wy) * s2 * (vy0 * vx1);
        const float w10 = (1.f - wx) * wy * s2 * (vy1 * vx0);
        const float w11 = wx * wy * s2 * (vy1 * vx1);
        const float4 v0 = *(const float4*)(fb + o00);
        const float4 v1 = *(const float4*)(fb + o01);
        const float4 v2 = *(const float4*)(fb + o10);
        const float4 v3 = *(const float4*)(fb + o11);
        ax = fmaf(w00, v0.x, ax); ay = fmaf(w00, v0.y, ay);
        az = fmaf(w00, v0.z, az); aw = fmaf(w00, v0.w, aw);
        ax = fmaf(w01, v1.x, ax); ay = fmaf(w01, v1.y, ay);
        az = fmaf(w01, v1.z, az); aw = fmaf(w01, v1.w, aw);
        ax = fmaf(w10, v2.x, ax); ay = fmaf(w10, v2.y, ay);
        az = fmaf(w10, v2.z, az); aw = fmaf(w10, v2.w, aw);
        ax = fmaf(w11, v3.x, ax); ay = fmaf(w11, v3.y, ay);
        az = fmaf(w11, v3.z, az); aw = fmaf(w11, v3.w, aw);
    }
    // combine this wave's 4 point-groups (lanes l, l^16, l^32, l^48)
    ax += __shfl_xor(ax, 16, 64); ay += __shfl_xor(ay, 16, 64);
    az += __shfl_xor(az, 16, 64); aw += __shfl_xor(aw, 16, 64);
    ax += __shfl_xor(ax, 32, 64); ay += __shfl_xor(ay, 32, 64);
    az += __shfl_xor(az, 32, 64); aw += __shfl_xor(aw, 32, 64);
    return make_float4(ax, ay, az, aw);
}

__global__ __launch_bounds__(256) void k_fused(
    const float* __restrict__ fm_t, const float* __restrict__ boxes,
    const float* __restrict__ w1, const float* __restrict__ b1,
    const float* __restrict__ w2, const float* __restrict__ b2,
    const float* __restrict__ p1, const float* __restrict__ f1pre,
    const float* __restrict__ p2, const float* __restrict__ pb2,
    float* __restrict__ out, int N)
{
    __shared__ __align__(16) float xpart[2][2][192]; // per-box per-half pooled partials
    __shared__ __align__(16) float xbuf[2][192];     // pooled [3][64] per box
    __shared__ __align__(16) float hbuf[2][384];     // H [3][128] per box
    __shared__ __align__(16) float cbuf[2][192];     // cat per box
    __shared__ __align__(16) float fbuf[2][128];     // F per box
    __shared__ __align__(16) float opart[2][2][64];  // L4 split-K partials

    const int t    = threadIdx.x;
    const int lane = t & 63;
    const int w    = t >> 6;        // wave 0..3
    const int n0   = blockIdx.x * 2;

    // ---------------- pool: 2 waves per box ----------------
    {
        const int b  = w >> 1;      // box slot 0..1
        const int hf = w & 1;       // which half of the points
        const int qc = lane & 15;   // channel quad
        const int pg = lane >> 4;   // point group within wave
        const int g8 = hf * 4 + pg; // global point group 0..7
        const int n  = n0 + b;

        if (n < N) {
            const float4 bx = reinterpret_cast<const float4*>(boxes)[n];
            const float x1 = bx.x / 960.f * 2.f - 1.f;
            const float y1 = bx.y / 960.f * 2.f - 1.f;
            const float x2 = bx.z / 960.f * 2.f - 1.f;
            const float y2 = bx.w / 960.f * 2.f - 1.f;
            const float cx  = (x1 + x2) * 0.5f;
            const float cy  = (y1 + y2) * 0.5f;
            const float bw2 = fmaxf(x2 - x1, 1e-6f) * 0.5f;
            const float bh2 = fmaxf(y2 - y1, 1e-6f) * 0.5f;
            const char* fb = (const char*)fm_t + qc * 16;

            const float4 r0 = gather8<3>(fb, g8, cx, cy, bw2, bh2);
            if (pg == 0) *(float4*)(&xpart[b][hf][4 * qc]) = r0;
            const float4 r1 = gather8<7>(fb, g8, cx, cy, bw2, bh2);
            if (pg == 0) *(float4*)(&xpart[b][hf][64 + 4 * qc]) = r1;
            const float4 r2 = gather8<11>(fb, g8, cx, cy, bw2, bh2);
            if (pg == 0) *(float4*)(&xpart[b][hf][128 + 4 * qc]) = r2;
        } else if (pg == 0) {
            const float4 z = make_float4(0.f, 0.f, 0.f, 0.f);
            *(float4*)(&xpart[b][hf][4 * qc]) = z;
            *(float4*)(&xpart[b][hf][64 + 4 * qc]) = z;
            *(float4*)(&xpart[b][hf][128 + 4 * qc]) = z;
        }
    }
    __syncthreads();

    // sum the two halves: 2 boxes x 192 = 384 values
    for (int i = t; i < 384; i += 256) {
        const int b = i / 192, r = i - b * 192;
        xbuf[b][r] = xpart[b][0][r] + xpart[b][1][r];
    }
    __syncthreads();

    // ---------------- L1: 2 boxes x 3 scales x 128 outs = 768 = 3 per thread ----
    {
        const int k  = t & 127;          // output column
        const int wp = t >> 7;           // 0..1
        // groups G = wp, wp+2, wp+4 -> (box = G/3, scale = G%3)
        const int G0 = wp,     b0 = G0 / 3, s0 = G0 - 3 * b0;
        const int G1 = wp + 2, b1_ = G1 / 3, s1_ = G1 - 3 * b1_;
        const int G2 = wp + 4, b2_ = G2 / 3, s2_ = G2 - 3 * b2_;
        const float* xb0 = xbuf[b0] + s0 * 64;
        const float* xb1 = xbuf[b1_] + s1_ * 64;
        const float* xb2 = xbuf[b2_] + s2_ * 64;
        const float bias = b1[k];
        float a0 = bias, a1 = bias, a2 = bias;
        #pragma unroll 4
        for (int c4 = 0; c4 < 16; ++c4) {
            const float4 xv0 = *(const float4*)(xb0 + 4 * c4);  // uniform -> bcast
            const float4 xv1 = *(const float4*)(xb1 + 4 * c4);
            const float4 xv2 = *(const float4*)(xb2 + 4 * c4);
            #define W1LD(CI) w1[(4 * c4 + CI) * 128 + k]
            { const float wv = W1LD(0);
              a0 = fmaf(xv0.x, wv, a0); a1 = fmaf(xv1.x, wv, a1); a2 = fmaf(xv2.x, wv, a2); }
            { const float wv = W1LD(1);
              a0 = fmaf(xv0.y, wv, a0); a1 = fmaf(xv1.y, wv, a1); a2 = fmaf(xv2.y, wv, a2); }
            { const float wv = W1LD(2);
              a0 = fmaf(xv0.z, wv, a0); a1 = fmaf(xv1.z, wv, a1); a2 = fmaf(xv2.z, wv, a2); }
            { const float wv = W1LD(3);
              a0 = fmaf(xv0.w, wv, a0); a1 = fmaf(xv1.w, wv, a1); a2 = fmaf(xv2.w, wv, a2); }
            #undef W1LD
        }
        hbuf[b0][s0 * 128 + k]   = fmaxf(a0, 0.f);
        hbuf[b1_][s1_ * 128 + k] = fmaxf(a1, 0.f);
        hbuf[b2_][s2_ * 128 + k] = fmaxf(a2, 0.f);
    }
    __syncthreads();

    // ---------------- L2: 2 boxes x 3 scales x 64 outs = 384 ----------------
    {
        const int co = lane;             // output column
        const float bias = b2[co];
        {   // rep0: G = t>>6 in 0..3
            const int G = t >> 6;
            const int b = G / 3, s = G - 3 * (G / 3);
            const float* hb = hbuf[b] + s * 128;
            float a = bias;
            #pragma unroll 4
            for (int c4 = 0; c4 < 32; ++c4) {
                const float4 hv = *(const float4*)(hb + 4 * c4);
                a = fmaf(hv.x, w2[(4 * c4 + 0) * 64 + co], a);
                a = fmaf(hv.y, w2[(4 * c4 + 1) * 64 + co], a);
                a = fmaf(hv.z, w2[(4 * c4 + 2) * 64 + co], a);
                a = fmaf(hv.w, w2[(4 * c4 + 3) * 64 + co], a);
            }
            cbuf[b][s * 64 + co] = fmaxf(a, 0.f);
        }
        if (t < 128) {  // rep1: G = 4 + (t>>6) in 4..5
            const int G = 4 + (t >> 6);
            const int b = G / 3, s = G - 3 * (G / 3);
            const float* hb = hbuf[b] + s * 128;
            float a = bias;
            #pragma unroll 4
            for (int c4 = 0; c4 < 32; ++c4) {
                const float4 hv = *(const float4*)(hb + 4 * c4);
                a = fmaf(hv.x, w2[(4 * c4 + 0) * 64 + co], a);
                a = fmaf(hv.y, w2[(4 * c4 + 1) * 64 + co], a);
                a = fmaf(hv.z, w2[(4 * c4 + 2) * 64 + co], a);
                a = fmaf(hv.w, w2[(4 * c4 + 3) * 64 + co], a);
            }
            cbuf[b][s * 64 + co] = fmaxf(a, 0.f);
        }
    }
    __syncthreads();

    // ---------------- L3: 2 boxes x 128 outs = 256 = 1 per thread ----------------
    {
        const int k = t & 127;
        const int b = t >> 7;
        const float* cb = cbuf[b];
        float a = f1pre[k];              // includes pb1 + global-branch term
        #pragma unroll 4
        for (int q4 = 0; q4 < 48; ++q4) {
            const float4 cv = *(const float4*)(cb + 4 * q4);
            a = fmaf(cv.x, p1[(4 * q4 + 0) * 128 + k], a);
            a = fmaf(cv.y, p1[(4 * q4 + 1) * 128 + k], a);
            a = fmaf(cv.z, p1[(4 * q4 + 2) * 128 + k], a);
            a = fmaf(cv.w, p1[(4 * q4 + 3) * 128 + k], a);
        }
        fbuf[b][k] = fmaxf(a, 0.f);
    }
    __syncthreads();

    // ---------------- L4: 2 boxes x 64 outs, K=128 split across 2 halves ----------
    {
        const int co = lane;
        const int bb = (t >> 6) & 1;     // box (uniform per wave)
        const int kh = t >> 7;           // K-half (uniform per wave)
        const float* fbp = fbuf[bb] + kh * 64;
        float a = kh ? 0.f : pb2[co];
        #pragma unroll 4
        for (int j4 = 0; j4 < 16; ++j4) {
            const float4 fv = *(const float4*)(fbp + 4 * j4);
            a = fmaf(fv.x, p2[(kh * 64 + 4 * j4 + 0) * 64 + co], a);
            a = fmaf(fv.y, p2[(kh * 64 + 4 * j4 + 1) * 64 + co], a);
            a = fmaf(fv.z, p2[(kh * 64 + 4 * j4 + 2) * 64 + co], a);
            a = fmaf(fv.w, p2[(kh * 64 + 4 * j4 + 3) * 64 + co], a);
        }
        opart[kh][bb][co] = a;
    }
    __syncthreads();
    if (t < 128) {
        const int co = lane;
        const int bb = t >> 6;
        const int n  = n0 + bb;
        if (n < N)
            out[n * 64 + co] = fmaxf(opart[0][bb][co] + opart[1][bb][co], 0.f);
    }
}

extern "C" void kernel_launch(void* const* d_in, const int* in_sizes, int n_in,
                              void* d_out, int out_size, void* d_ws, size_t ws_size,
                              hipStream_t stream)
{
    const float* fm    = (const float*)d_in[0];
    const float* boxes = (const float*)d_in[1];
    const float* w1    = (const float*)d_in[2];
    const float* b1    = (const float*)d_in[3];
    const float* w2    = (const float*)d_in[4];
    const float* b2    = (const float*)d_in[5];
    const float* p1    = (const float*)d_in[6];
    const float* pb1   = (const float*)d_in[7];
    const float* p2    = (const float*)d_in[8];
    const float* pb2   = (const float*)d_in[9];
    float* out = (float*)d_out;

    const int N = in_sizes[1] / 4;       // 4096

    float* ws      = (float*)d_ws;
    float* fm_t    = ws;                         // 921600 floats
    float* partial = fm_t + 921600;              // 14400
    float* f1pre   = partial + 14400;            // 128

    k_transpose_mean<<<NPIX / 64, 256, 0, stream>>>(fm, fm_t, partial);
    k_ghead<<<1, 256, 0, stream>>>(partial, w1, b1, w2, b2, p1, pb1, f1pre);
    k_fused<<<(N + 1) / 2, 256, 0, stream>>>(fm_t, boxes, w1, b1, w2, b2,
                                             p1, f1pre, p2, pb2, out, N);
}

// Round 10
// 156.606 us; speedup vs baseline: 1.0364x; 1.0245x over previous
//
#include <hip/hip_runtime.h>
#include <hip/hip_bf16.h>

// EfficientMultiScaleROIExtractor for MI355X (gfx950)
// fm: [1,64,120,120] f32, boxes: [4096,4] f32, MLP weights f32.
//
// K1 k_transpose_mean: CHW->HWC + per-block channel partial sums
// K2 k_ghead: global mean -> shared head -> folded f1 bias (f1pre[128])
// K3 k_pool: pooling ONLY (r9 structure). 2 waves/box, 8 point-groups of
//    16 lanes, inline per-point math, 1KB coalesced 4-point gathers,
//    shfl + LDS combine, write pooled[3][N][64].
// K4 k_mlp: 256 blocks x 512 threads x 16 boxes. Weight traffic amortized
//    16x: 192KB of weights per block x 256 blocks = 49MB L2 (fused r9
//    paid 1.07GB re-fetching weights per 2-box block - that WAS the 72us).
//    Statically-unrolled register accumulators; activations via
//    wave-uniform ds_read_b128; weights 256B-coalesced.

#define HW 120
#define NPIX (HW * HW)   // 14400

__global__ __launch_bounds__(256) void k_transpose_mean(
    const float* __restrict__ fm, float* __restrict__ fm_t,
    float* __restrict__ partial)
{
    __shared__ float tile[64][65];
    __shared__ float pr[4][64];
    const int t  = threadIdx.x;
    const int tx = t & 63;
    const int ty = t >> 6;
    const int pix0 = blockIdx.x * 64;   // 225 blocks * 64 pixels = 14400

    #pragma unroll
    for (int k = 0; k < 16; ++k) {
        const int c = k * 4 + ty;
        tile[c][tx] = fm[c * NPIX + pix0 + tx];   // coalesced read
    }
    __syncthreads();
    #pragma unroll
    for (int k = 0; k < 16; ++k) {
        const int p = k * 4 + ty;
        fm_t[(pix0 + p) * 64 + tx] = tile[tx][p]; // coalesced write
    }
    float s = 0.f;
    #pragma unroll
    for (int k = 0; k < 16; ++k) s += tile[tx][ty * 16 + k];
    pr[ty][tx] = s;
    __syncthreads();
    if (t < 64)
        partial[blockIdx.x * 64 + t] = pr[0][t] + pr[1][t] + pr[2][t] + pr[3][t];
}

__global__ __launch_bounds__(256) void k_ghead(
    const float* __restrict__ partial,
    const float* __restrict__ w1, const float* __restrict__ b1,
    const float* __restrict__ w2, const float* __restrict__ b2,
    const float* __restrict__ p1, const float* __restrict__ pb1,
    float* __restrict__ f1pre)
{
    __shared__ float pr[4][64];
    __shared__ float g[64];
    __shared__ float h[128];
    __shared__ float gh[64];
    const int t = threadIdx.x;
    const int c = t & 63, q = t >> 6;
    float s = 0.f;
    for (int b = q; b < 225; b += 4) s += partial[b * 64 + c];
    pr[q][c] = s;
    __syncthreads();
    if (t < 64) g[t] = (pr[0][t] + pr[1][t] + pr[2][t] + pr[3][t]) * (1.f / 14400.f);
    __syncthreads();
    if (t < 128) {
        float a = b1[t];
        #pragma unroll 8
        for (int cc = 0; cc < 64; ++cc) a = fmaf(g[cc], w1[cc * 128 + t], a);
        h[t] = fmaxf(a, 0.f);
    }
    __syncthreads();
    if (t < 64) {
        float a = b2[t];
        #pragma unroll 8
        for (int k = 0; k < 128; ++k) a = fmaf(h[k], w2[k * 64 + t], a);
        gh[t] = fmaxf(a, 0.f);
    }
    __syncthreads();
    if (t < 128) {
        float a = pb1[t];
        #pragma unroll 8
        for (int j = 0; j < 64; ++j) a = fmaf(gh[j], p1[(192 + j) * 128 + t], a);
        f1pre[t] = a;   // no relu: relu happens after cat@p1 contribution
    }
}

// One scale's gather with 8 point-groups (2 waves per box). Each 16-lane
// group walks lp = g8, g8+8, ... recomputing the point's bilinear setup
// inline (lockstep within the group).
template <int R>
__device__ __forceinline__ float4 gather8(
    const char* __restrict__ fb, int g8,
    float cx, float cy, float bw2, float bh2)
{
    constexpr float invR = 1.f / (float)R;
    constexpr float s2   = invR * invR;          // folds the mean
    float ax = 0.f, ay = 0.f, az = 0.f, aw = 0.f;
    #pragma unroll 2
    for (int lp = g8; lp < R * R; lp += 8) {
        const int i = lp / R;                    // constexpr R -> magic mul
        const int j = lp - i * R;
        const float liny = (float)(2 * i + 1) * invR - 1.f;
        const float linx = (float)(2 * j + 1) * invR - 1.f;
        const float gy = cy + bh2 * liny;
        const float gx = cx + bw2 * linx;
        const float iy = ((gy + 1.f) * 120.f - 1.f) * 0.5f;
        const float ix = ((gx + 1.f) * 120.f - 1.f) * 0.5f;
        const float y0f = floorf(iy), x0f = floorf(ix);
        const float wy = iy - y0f,  wx = ix - x0f;
        const int y0 = (int)y0f, x0 = (int)x0f;
        const float vy0 = (y0 >= 0 && y0 < HW)      ? 1.f : 0.f;
        const float vy1 = (y0 >= -1 && y0 < HW - 1) ? 1.f : 0.f;
        const float vx0 = (x0 >= 0 && x0 < HW)      ? 1.f : 0.f;
        const float vx1 = (x0 >= -1 && x0 < HW - 1) ? 1.f : 0.f;
        const int x0c = min(max(x0, 0), HW - 1);
        const int x1c = min(max(x0 + 1, 0), HW - 1);
        const int y0c = min(max(y0, 0), HW - 1);
        const int y1c = min(max(y0 + 1, 0), HW - 1);
        const int o00 = (y0c * HW + x0c) * 256;  // one HWC pixel = 256B
        const int o01 = (y0c * HW + x1c) * 256;
        const int o10 = (y1c * HW + x0c) * 256;
        const int o11 = (y1c * HW + x1c) * 256;
        const float w00 = (1.f - wx) * (1.f - wy) * s2 * (vy0 * vx0);
        const float w01 = wx * (1.f - wy) * s2 * (vy0 * vx1);
        const float w10 = (1.f - wx) * wy * s2 * (vy1 * vx0);
        const float w11 = wx * wy * s2 * (vy1 * vx1);
        const float4 v0 = *(const float4*)(fb + o00);
        const float4 v1 = *(const float4*)(fb + o01);
        const float4 v2 = *(const float4*)(fb + o10);
        const float4 v3 = *(const float4*)(fb + o11);
        ax = fmaf(w00, v0.x, ax); ay = fmaf(w00, v0.y, ay);
        az = fmaf(w00, v0.z, az); aw = fmaf(w00, v0.w, aw);
        ax = fmaf(w01, v1.x, ax); ay = fmaf(w01, v1.y, ay);
        az = fmaf(w01, v1.z, az); aw = fmaf(w01, v1.w, aw);
        ax = fmaf(w10, v2.x, ax); ay = fmaf(w10, v2.y, ay);
        az = fmaf(w10, v2.z, az); aw = fmaf(w10, v2.w, aw);
        ax = fmaf(w11, v3.x, ax); ay = fmaf(w11, v3.y, ay);
        az = fmaf(w11, v3.z, az); aw = fmaf(w11, v3.w, aw);
    }
    // combine this wave's 4 point-groups (lanes l, l^16, l^32, l^48)
    ax += __shfl_xor(ax, 16, 64); ay += __shfl_xor(ay, 16, 64);
    az += __shfl_xor(az, 16, 64); aw += __shfl_xor(aw, 16, 64);
    ax += __shfl_xor(ax, 32, 64); ay += __shfl_xor(ay, 32, 64);
    az += __shfl_xor(az, 32, 64); aw += __shfl_xor(aw, 32, 64);
    return make_float4(ax, ay, az, aw);
}

__global__ __launch_bounds__(256) void k_pool(
    const float* __restrict__ fm_t, const float* __restrict__ boxes,
    float* __restrict__ pooled, int N)
{
    __shared__ __align__(16) float xpart[2][2][192]; // [box][half][s*64+c]

    const int t    = threadIdx.x;
    const int lane = t & 63;
    const int w    = t >> 6;        // wave 0..3
    const int n0   = blockIdx.x * 2;

    {
        const int b  = w >> 1;      // box slot 0..1
        const int hf = w & 1;       // which half of the points
        const int qc = lane & 15;   // channel quad
        const int pg = lane >> 4;   // point group within wave
        const int g8 = hf * 4 + pg; // global point group 0..7
        const int n  = n0 + b;

        if (n < N) {
            const float4 bx = reinterpret_cast<const float4*>(boxes)[n];
            const float x1 = bx.x / 960.f * 2.f - 1.f;
            const float y1 = bx.y / 960.f * 2.f - 1.f;
            const float x2 = bx.z / 960.f * 2.f - 1.f;
            const float y2 = bx.w / 960.f * 2.f - 1.f;
            const float cx  = (x1 + x2) * 0.5f;
            const float cy  = (y1 + y2) * 0.5f;
            const float bw2 = fmaxf(x2 - x1, 1e-6f) * 0.5f;
            const float bh2 = fmaxf(y2 - y1, 1e-6f) * 0.5f;
            const char* fb = (const char*)fm_t + qc * 16;

            const float4 r0 = gather8<3>(fb, g8, cx, cy, bw2, bh2);
            if (pg == 0) *(float4*)(&xpart[b][hf][4 * qc]) = r0;
            const float4 r1 = gather8<7>(fb, g8, cx, cy, bw2, bh2);
            if (pg == 0) *(float4*)(&xpart[b][hf][64 + 4 * qc]) = r1;
            const float4 r2 = gather8<11>(fb, g8, cx, cy, bw2, bh2);
            if (pg == 0) *(float4*)(&xpart[b][hf][128 + 4 * qc]) = r2;
        }
    }
    __syncthreads();

    // combine halves and write pooled[s][n][64]
    for (int i = t; i < 384; i += 256) {
        const int b = i / 192, r = i - b * 192;
        const int n = n0 + b;
        if (n < N) {
            const int s = r >> 6, c = r & 63;
            pooled[(s * N + n) * 64 + c] = xpart[b][0][r] + xpart[b][1][r];
        }
    }
}

// 16 boxes/block, 512 threads. Weight loads 256B-coalesced, amortized over
// 12/6/4/2 register accumulators. Activations: wave-uniform ds_read_b128.
__global__ __launch_bounds__(512) void k_mlp(
    const float* __restrict__ pooled,
    const float* __restrict__ w1, const float* __restrict__ b1,
    const float* __restrict__ w2, const float* __restrict__ b2,
    const float* __restrict__ p1, const float* __restrict__ f1pre,
    const float* __restrict__ p2, const float* __restrict__ pb2,
    float* __restrict__ out, int N)
{
    __shared__ __align__(16) float xls[48 * 64];    // [P=b*3+s][64]
    __shared__ __align__(16) float hls[48 * 128];   // [P][128]
    __shared__ __align__(16) float cls[16 * 192];   // [b][s*64+co]
    __shared__ __align__(16) float fls[16 * 128];   // [b][128]
    __shared__ float f1b[128];

    const int t  = threadIdx.x;
    const int n0 = blockIdx.x * 16;

    // stage pooled -> xls (float4 granules), f1pre -> f1b
    for (int i = t; i < 768; i += 512) {     // 768 float4 = 3072 floats
        const int f = i * 4;
        const int P = f >> 6;
        const int c = f & 63;
        const int b = P / 3;
        const int s = P - 3 * b;
        const int n = n0 + b;
        float4 v = make_float4(0.f, 0.f, 0.f, 0.f);
        if (n < N) v = *(const float4*)(pooled + (s * N + n) * 64 + c);
        *(float4*)(xls + f) = v;
    }
    if (t < 128) f1b[t] = f1pre[t];
    __syncthreads();

    // ---- L1: 48 pairs x 128 outs = 6144 -> 12 acc/thread ----
    {
        const int k = t & 127;
        const int g = t >> 7;            // wave-pair 0..3 (wave-uniform)
        const float bias = b1[k];
        float acc[12];
        #pragma unroll
        for (int r = 0; r < 12; ++r) acc[r] = bias;
        #pragma unroll 2
        for (int c4 = 0; c4 < 16; ++c4) {
            const float wv0 = w1[(4 * c4 + 0) * 128 + k];
            const float wv1 = w1[(4 * c4 + 1) * 128 + k];
            const float wv2 = w1[(4 * c4 + 2) * 128 + k];
            const float wv3 = w1[(4 * c4 + 3) * 128 + k];
            #pragma unroll
            for (int r = 0; r < 12; ++r) {
                const float4 xv = *(const float4*)(xls + (g + 4 * r) * 64 + 4 * c4);
                acc[r] = fmaf(xv.x, wv0, acc[r]);
                acc[r] = fmaf(xv.y, wv1, acc[r]);
                acc[r] = fmaf(xv.z, wv2, acc[r]);
                acc[r] = fmaf(xv.w, wv3, acc[r]);
            }
        }
        #pragma unroll
        for (int r = 0; r < 12; ++r)
            hls[(g + 4 * r) * 128 + k] = fmaxf(acc[r], 0.f);
    }
    __syncthreads();

    // ---- L2: 48 pairs x 64 outs = 3072 -> 6 acc/thread ----
    {
        const int co = t & 63;
        const int w8 = t >> 6;           // wave 0..7 (uniform)
        const float bias = b2[co];
        float acc[6];
        #pragma unroll
        for (int r = 0; r < 6; ++r) acc[r] = bias;
        #pragma unroll 2
        for (int c4 = 0; c4 < 32; ++c4) {
            const float wv0 = w2[(4 * c4 + 0) * 64 + co];
            const float wv1 = w2[(4 * c4 + 1) * 64 + co];
            const float wv2 = w2[(4 * c4 + 2) * 64 + co];
            const float wv3 = w2[(4 * c4 + 3) * 64 + co];
            #pragma unroll
            for (int r = 0; r < 6; ++r) {
                const float4 hv = *(const float4*)(hls + (w8 + 8 * r) * 128 + 4 * c4);
                acc[r] = fmaf(hv.x, wv0, acc[r]);
                acc[r] = fmaf(hv.y, wv1, acc[r]);
                acc[r] = fmaf(hv.z, wv2, acc[r]);
                acc[r] = fmaf(hv.w, wv3, acc[r]);
            }
        }
        #pragma unroll
        for (int r = 0; r < 6; ++r) {
            const int P = w8 + 8 * r;
            const int b = P / 3;
            const int s = P - 3 * b;
            cls[b * 192 + s * 64 + co] = fmaxf(acc[r], 0.f);
        }
    }
    __syncthreads();

    // ---- L3: 16 boxes x 128 outs = 2048 -> 4 acc/thread ----
    {
        const int k = t & 127;
        const int g = t >> 7;            // 0..3 (uniform)
        const float bias = f1b[k];       // pb1 + global-branch folded
        float acc[4];
        #pragma unroll
        for (int r = 0; r < 4; ++r) acc[r] = bias;
        #pragma unroll 2
        for (int q4 = 0; q4 < 48; ++q4) {
            const float wv0 = p1[(4 * q4 + 0) * 128 + k];
            const float wv1 = p1[(4 * q4 + 1) * 128 + k];
            const float wv2 = p1[(4 * q4 + 2) * 128 + k];
            const float wv3 = p1[(4 * q4 + 3) * 128 + k];
            #pragma unroll
            for (int r = 0; r < 4; ++r) {
                const float4 cv = *(const float4*)(cls + (g + 4 * r) * 192 + 4 * q4);
                acc[r] = fmaf(cv.x, wv0, acc[r]);
                acc[r] = fmaf(cv.y, wv1, acc[r]);
                acc[r] = fmaf(cv.z, wv2, acc[r]);
                acc[r] = fmaf(cv.w, wv3, acc[r]);
            }
        }
        #pragma unroll
        for (int r = 0; r < 4; ++r)
            fls[(g + 4 * r) * 128 + k] = fmaxf(acc[r], 0.f);
    }
    __syncthreads();

    // ---- L4: 16 boxes x 64 outs = 1024 -> 2 acc/thread ----
    {
        const int co = t & 63;
        const int w8 = t >> 6;           // 0..7 (uniform); boxes w8, w8+8
        float a0 = pb2[co], a1 = a0;
        #pragma unroll 2
        for (int j4 = 0; j4 < 32; ++j4) {
            const float wv0 = p2[(4 * j4 + 0) * 64 + co];
            const float wv1 = p2[(4 * j4 + 1) * 64 + co];
            const float wv2 = p2[(4 * j4 + 2) * 64 + co];
            const float wv3 = p2[(4 * j4 + 3) * 64 + co];
            const float4 f0 = *(const float4*)(fls + w8 * 128 + 4 * j4);
            const float4 f1v = *(const float4*)(fls + (w8 + 8) * 128 + 4 * j4);
            a0 = fmaf(f0.x, wv0, a0);  a1 = fmaf(f1v.x, wv0, a1);
            a0 = fmaf(f0.y, wv1, a0);  a1 = fmaf(f1v.y, wv1, a1);
            a0 = fmaf(f0.z, wv2, a0);  a1 = fmaf(f1v.z, wv2, a1);
            a0 = fmaf(f0.w, wv3, a0);  a1 = fmaf(f1v.w, wv3, a1);
        }
        const int na = n0 + w8;
        const int nb = n0 + w8 + 8;
        if (na < N) out[na * 64 + co] = fmaxf(a0, 0.f);
        if (nb < N) out[nb * 64 + co] = fmaxf(a1, 0.f);
    }
}

extern "C" void kernel_launch(void* const* d_in, const int* in_sizes, int n_in,
                              void* d_out, int out_size, void* d_ws, size_t ws_size,
                              hipStream_t stream)
{
    const float* fm    = (const float*)d_in[0];
    const float* boxes = (const float*)d_in[1];
    const float* w1    = (const float*)d_in[2];
    const float* b1    = (const float*)d_in[3];
    const float* w2    = (const float*)d_in[4];
    const float* b2    = (const float*)d_in[5];
    const float* p1    = (const float*)d_in[6];
    const float* pb1   = (const float*)d_in[7];
    const float* p2    = (const float*)d_in[8];
    const float* pb2   = (const float*)d_in[9];
    float* out = (float*)d_out;

    const int N = in_sizes[1] / 4;       // 4096

    float* ws      = (float*)d_ws;
    float* fm_t    = ws;                         // 921600 floats
    float* partial = fm_t + 921600;              // 14400
    float* f1pre   = partial + 14400;            // 128
    float* pooled  = f1pre + 128;                // 3*N*64

    k_transpose_mean<<<NPIX / 64, 256, 0, stream>>>(fm, fm_t, partial);
    k_ghead<<<1, 256, 0, stream>>>(partial, w1, b1, w2, b2, p1, pb1, f1pre);
    k_pool<<<(N + 1) / 2, 256, 0, stream>>>(fm_t, boxes, pooled, N);
    k_mlp<<<(N + 15) / 16, 512, 0, stream>>>(pooled, w1, b1, w2, b2,
                                             p1, f1pre, p2, pb2, out, N);
}